// Round 1
// baseline (123.089 us; speedup 1.0000x reference)
//
#include <hip/hip_runtime.h>
#include <hip/hip_bf16.h>

// out[b,s,t] = ||B(x_s - x_t)||^2 = sq[s] + sq[t] - 2*gram[s,t],  p = x @ B^T
// Pipeline: cvt_b -> proj GEMM (p bf16) -> sq -> batched gram GEMM + epilogue.

using bf16x8 = __attribute__((ext_vector_type(8))) __bf16;
using f32x4  = __attribute__((ext_vector_type(4))) float;
using fl4    = __attribute__((ext_vector_type(4))) float;
using u16x4  = __attribute__((ext_vector_type(4))) unsigned short;

#define NB 64
#define NS 512
#define NL 768
#define NM (NB * NS) // 32768 projected rows

__device__ __forceinline__ unsigned short f2bf(float f) {
  unsigned u = __builtin_bit_cast(unsigned, f);
  u += 0x7FFFu + ((u >> 16) & 1u); // RNE
  return (unsigned short)(u >> 16);
}

__device__ __forceinline__ void gload_lds16(const void* g, void* l) {
  __builtin_amdgcn_global_load_lds(
      (const __attribute__((address_space(1))) void*)g,
      (__attribute__((address_space(3))) void*)l, 16, 0, 0);
}

// ---------------- kernel 1: convert b (L x L fp32) -> bb bf16 ----------------
__global__ __launch_bounds__(256) void k_cvt_b(const float* __restrict__ b,
                                               unsigned short* __restrict__ bb) {
  const long t = (long)blockIdx.x * 256 + threadIdx.x; // one float4 each
  fl4 v = *(const fl4*)(b + t * 4);
  u16x4 o;
#pragma unroll
  for (int j = 0; j < 4; ++j) o[j] = f2bf(v[j]);
  *(u16x4*)(bb + t * 4) = o;
}

// ---------------- kernel 2: p[M,L] = x[M,L] @ bb^T (NT GEMM) ----------------
// 128x128 tile, BK=32, 4 waves (each 64x64 = 4x4 frags of 16x16x32).
__global__ __launch_bounds__(256) void k_proj(const float* __restrict__ x,
                                              const unsigned short* __restrict__ bb,
                                              unsigned short* __restrict__ p) {
  __shared__ unsigned short smA[128 * 32];
  __shared__ unsigned short smB[128 * 32];
  const int tid = threadIdx.x;
  const int w = tid >> 6, l = tid & 63;
  // XCD-chunked swizzle (1536 blocks, 8 XCDs, 192/XCD), consecutive wg share m-tile
  const int wg = ((blockIdx.x & 7) * 192) + (blockIdx.x >> 3);
  const int nt = wg % 6, mt = wg / 6;
  const long m0 = (long)mt * 128, n0 = (long)nt * 128;
  const int wr = (w >> 1) * 64, wc = (w & 1) * 64;

  // A staging (fp32 -> bf16 via regs): thread covers flat elems f = i*1024 + tid*4
  const int arow = tid >> 3;          // f/32 for i=0
  const int akk  = (tid & 7) * 4;
  const float* gA = x + (m0 + arow) * NL + akk;
  // B staging via global_load_lds: round r: row = tid/4 + r*64, 8 bf16 per lane
  const int brow = tid >> 2;
  const int bkq  = (tid & 3) * 8;
  const unsigned short* gB = bb + (n0 + brow) * (long)NL + bkq;
  char* ldsB0 = (char*)smB + w * 1024; // wave-uniform base; HW adds lane*16

  const int qh = l >> 4, lr = l & 15;
  const int aoff = (wr + lr) * 64 + qh * 16; // byte offset in smA, + m*1024
  const int boff = (wc + lr) * 64 + qh * 16;

  f32x4 acc[4][4] = {};
#pragma unroll 1
  for (int kt = 0; kt < 24; ++kt) {
    const int k0 = kt * 32;
    __syncthreads(); // previous tile consumed
    gload_lds16(gB + k0, ldsB0);
    gload_lds16(gB + k0 + 64 * NL, ldsB0 + 4096);
    fl4 va0 = *(const fl4*)(gA + k0);
    fl4 va1 = *(const fl4*)(gA + k0 + 32 * NL);
    fl4 va2 = *(const fl4*)(gA + k0 + 64 * NL);
    fl4 va3 = *(const fl4*)(gA + k0 + 96 * NL);
    u16x4 o0, o1, o2, o3;
#pragma unroll
    for (int j = 0; j < 4; ++j) {
      o0[j] = f2bf(va0[j]); o1[j] = f2bf(va1[j]);
      o2[j] = f2bf(va2[j]); o3[j] = f2bf(va3[j]);
    }
    *(u16x4*)((char*)smA + 0 * 2048 + tid * 8) = o0;
    *(u16x4*)((char*)smA + 1 * 2048 + tid * 8) = o1;
    *(u16x4*)((char*)smA + 2 * 2048 + tid * 8) = o2;
    *(u16x4*)((char*)smA + 3 * 2048 + tid * 8) = o3;
    __syncthreads(); // staging complete (drains vmcnt+lgkm)
    bf16x8 fa[4], fb[4];
#pragma unroll
    for (int m = 0; m < 4; ++m)
      fa[m] = *(const bf16x8*)((const char*)smA + aoff + m * 1024);
#pragma unroll
    for (int n = 0; n < 4; ++n)
      fb[n] = *(const bf16x8*)((const char*)smB + boff + n * 1024);
#pragma unroll
    for (int m = 0; m < 4; ++m)
#pragma unroll
      for (int n = 0; n < 4; ++n)
        acc[m][n] = __builtin_amdgcn_mfma_f32_16x16x32_bf16(fa[m], fb[n], acc[m][n], 0, 0, 0);
  }
  // epilogue: C/D layout col = lane&15, row = (lane>>4)*4 + reg  [m89]
#pragma unroll
  for (int m = 0; m < 4; ++m) {
    const long rbase = m0 + wr + m * 16 + qh * 4;
#pragma unroll
    for (int n = 0; n < 4; ++n) {
      const long col = n0 + wc + n * 16 + lr;
#pragma unroll
      for (int r = 0; r < 4; ++r)
        p[(rbase + r) * NL + col] = f2bf(acc[m][n][r]);
    }
  }
}

// ---------------- kernel 3: sq[i] = sum_g p[i,g]^2 ----------------
__global__ __launch_bounds__(256) void k_sq(const unsigned short* __restrict__ p,
                                            float* __restrict__ sq) {
  const int row = blockIdx.x * 4 + (threadIdx.x >> 6);
  const int l = threadIdx.x & 63;
  const unsigned short* pr = p + (long)row * NL;
  float s = 0.f;
#pragma unroll
  for (int c = 0; c < 3; ++c) {
    u16x4 v = *(const u16x4*)(pr + (c * 64 + l) * 4);
#pragma unroll
    for (int j = 0; j < 4; ++j) {
      float f = __builtin_bit_cast(float, ((unsigned)v[j]) << 16);
      s += f * f;
    }
  }
#pragma unroll
  for (int d = 32; d >= 1; d >>= 1) s += __shfl_xor(s, d, 64);
  if (l == 0) sq[row] = s;
}

// ------- kernel 4: per-batch gram + epilogue sq[s]+sq[t]-2*gram -------
__global__ __launch_bounds__(256) void k_gram(const unsigned short* __restrict__ p,
                                              const float* __restrict__ sq,
                                              float* __restrict__ out) {
  __shared__ unsigned short smA[128 * 32];
  __shared__ unsigned short smB[128 * 32];
  const int tid = threadIdx.x;
  const int w = tid >> 6, l = tid & 63;
  // 1024 blocks, 128/XCD; consecutive wg share a batch (p_b stays in L2)
  const int wg = ((blockIdx.x & 7) * 128) + (blockIdx.x >> 3);
  const int batch = wg >> 4, tile = wg & 15;
  const int mt = tile >> 2, nt = tile & 3;
  const unsigned short* pb = p + (long)batch * NS * NL;
  const long m0 = (long)mt * 128, n0 = (long)nt * 128;
  const int wr = (w >> 1) * 64, wc = (w & 1) * 64;

  const int srow = tid >> 2;
  const int skq  = (tid & 3) * 8;
  const unsigned short* gA = pb + (m0 + srow) * (long)NL + skq;
  const unsigned short* gB = pb + (n0 + srow) * (long)NL + skq;
  char* ldsA0 = (char*)smA + w * 1024;
  char* ldsB0 = (char*)smB + w * 1024;

  const int qh = l >> 4, lr = l & 15;
  const int aoff = (wr + lr) * 64 + qh * 16;
  const int boff = (wc + lr) * 64 + qh * 16;

  f32x4 acc[4][4] = {};
#pragma unroll 1
  for (int kt = 0; kt < 24; ++kt) {
    const int k0 = kt * 32;
    __syncthreads();
    gload_lds16(gA + k0, ldsA0);
    gload_lds16(gA + k0 + 64 * NL, ldsA0 + 4096);
    gload_lds16(gB + k0, ldsB0);
    gload_lds16(gB + k0 + 64 * NL, ldsB0 + 4096);
    __syncthreads();
    bf16x8 fa[4], fb[4];
#pragma unroll
    for (int m = 0; m < 4; ++m)
      fa[m] = *(const bf16x8*)((const char*)smA + aoff + m * 1024);
#pragma unroll
    for (int n = 0; n < 4; ++n)
      fb[n] = *(const bf16x8*)((const char*)smB + boff + n * 1024);
#pragma unroll
    for (int m = 0; m < 4; ++m)
#pragma unroll
      for (int n = 0; n < 4; ++n)
        acc[m][n] = __builtin_amdgcn_mfma_f32_16x16x32_bf16(fa[m], fb[n], acc[m][n], 0, 0, 0);
  }
  const float* sqb = sq + batch * NS;
  float* outb = out + (long)batch * NS * NS;
  float sqc[4];
#pragma unroll
  for (int n = 0; n < 4; ++n) sqc[n] = sqb[n0 + wc + n * 16 + lr];
#pragma unroll
  for (int m = 0; m < 4; ++m) {
#pragma unroll
    for (int r = 0; r < 4; ++r) {
      const long row = m0 + wr + m * 16 + qh * 4 + r;
      const float sr = sqb[row];
#pragma unroll
      for (int n = 0; n < 4; ++n) {
        const long col = n0 + wc + n * 16 + lr;
        outb[row * NS + col] = sr + sqc[n] - 2.0f * acc[m][n][r];
      }
    }
  }
}

extern "C" void kernel_launch(void* const* d_in, const int* in_sizes, int n_in,
                              void* d_out, int out_size, void* d_ws, size_t ws_size,
                              hipStream_t stream) {
  (void)in_sizes; (void)n_in; (void)out_size; (void)ws_size;
  const float* x = (const float*)d_in[0]; // [B,S,L] fp32
  const float* b = (const float*)d_in[1]; // [L,L] fp32
  float* out = (float*)d_out;             // [B,S,S] fp32
  char* ws = (char*)d_ws;
  // ws layout (needs ~49.3 MiB):
  unsigned short* bb = (unsigned short*)ws;              // 1,179,648 B
  float* sq          = (float*)(ws + 1179648);           //   131,072 B
  unsigned short* p  = (unsigned short*)(ws + 1310720);  // 50,331,648 B

  k_cvt_b<<<576, 256, 0, stream>>>(b, bb);       // 576*256*4 = 589824 = L*L
  k_proj <<<1536, 256, 0, stream>>>(x, bb, p);   // 256 m-tiles * 6 n-tiles
  k_sq   <<<8192, 256, 0, stream>>>(p, sq);      // 32768 rows / 4
  k_gram <<<1024, 256, 0, stream>>>(p, sq, out); // 64 batches * 16 tiles
}

// Round 2
// 118.691 us; speedup vs baseline: 1.0371x; 1.0371x over previous
//
#include <hip/hip_runtime.h>
#include <hip/hip_bf16.h>

// out[b,s,t] = ||B(x_s - x_t)||^2 = sq[s] + sq[t] - 2*gram[s,t],  p = x @ B^T
// Round 2: k_proj stages A as fp32 via global_load_lds (cvt at frag-load),
// min-2-phase double-buffer + rule-#21 swizzle on both GEMMs.

using bf16x8 = __attribute__((ext_vector_type(8))) __bf16;
using f32x4  = __attribute__((ext_vector_type(4))) float;
using fl4    = __attribute__((ext_vector_type(4))) float;
using u16x4  = __attribute__((ext_vector_type(4))) unsigned short;
using u32x4  = __attribute__((ext_vector_type(4))) unsigned int;

#define NB 64
#define NS 512
#define NL 768

__device__ __forceinline__ unsigned short f2bf(float f) {
  unsigned u = __builtin_bit_cast(unsigned, f);
  u += 0x7FFFu + ((u >> 16) & 1u); // RNE
  return (unsigned short)(u >> 16);
}

__device__ __forceinline__ void gload_lds16(const void* g, void* l) {
  __builtin_amdgcn_global_load_lds(
      (const __attribute__((address_space(1))) void*)g,
      (__attribute__((address_space(3))) void*)l, 16, 0, 0);
}

__device__ __forceinline__ bf16x8 cvt_bf8(fl4 a, fl4 b) {
  unsigned r0, r1, r2, r3;
  asm("v_cvt_pk_bf16_f32 %0, %1, %2" : "=v"(r0) : "v"(a[0]), "v"(a[1]));
  asm("v_cvt_pk_bf16_f32 %0, %1, %2" : "=v"(r1) : "v"(a[2]), "v"(a[3]));
  asm("v_cvt_pk_bf16_f32 %0, %1, %2" : "=v"(r2) : "v"(b[0]), "v"(b[1]));
  asm("v_cvt_pk_bf16_f32 %0, %1, %2" : "=v"(r3) : "v"(b[2]), "v"(b[3]));
  u32x4 t = {r0, r1, r2, r3};
  return __builtin_bit_cast(bf16x8, t);
}

// ---------------- kernel 1: convert b (L x L fp32) -> bb bf16 ----------------
__global__ __launch_bounds__(256) void k_cvt_b(const float* __restrict__ b,
                                               unsigned short* __restrict__ bb) {
  const long t = (long)blockIdx.x * 256 + threadIdx.x;
  fl4 v = *(const fl4*)(b + t * 4);
  u16x4 o;
#pragma unroll
  for (int j = 0; j < 4; ++j) o[j] = f2bf(v[j]);
  *(u16x4*)(bb + t * 4) = o;
}

// ---------------- kernel 2: p[M,L] = x[M,L] @ bb^T ----------------
// 128x128 tile, BK=32, 4 waves. A staged fp32 (128B rows, 3-bit XOR swizzle),
// B staged bf16 (64B rows, 2-bit XOR swizzle). Double-buffered, 1 barrier/iter.
__global__ __launch_bounds__(256) void k_proj(const float* __restrict__ x,
                                              const unsigned short* __restrict__ bb,
                                              unsigned short* __restrict__ p) {
  __shared__ __align__(16) float          smA[2][128 * 32]; // 32 KB
  __shared__ __align__(16) unsigned short smB[2][128 * 32]; // 16 KB
  const int tid = threadIdx.x;
  const int w = tid >> 6, l = tid & 63;
  const int wg = ((blockIdx.x & 7) * 192) + (blockIdx.x >> 3);
  const int nt = wg % 6, mt = wg / 6;
  const long m0 = (long)mt * 128, n0 = (long)nt * 128;
  const int wr = (w >> 1) * 64, wc = (w & 1) * 64;

  // A stage: call c covers rows c*32 + tid/8; source col pre-swizzled (rule #21)
  const int arow = tid >> 3;
  const int acol = ((tid & 7) ^ (arow & 7)) * 4; // floats within the 32-col K-slice
  const float* gA = x + (m0 + arow) * (long)NL + acol;
  // B stage: call c covers rows c*64 + tid/4
  const int brow = tid >> 2;
  const int bcol = ((tid & 3) ^ (brow & 3)) * 8; // shorts
  const unsigned short* gB = bb + (n0 + brow) * (long)NL + bcol;

  const int qh = l >> 4, lr = l & 15;
  const int aoff = (wr + lr) * 128;                 // A row byte base (fp32, 128B rows)
  const int asw1 = (qh * 32) ^ ((lr & 7) << 4);     // swizzled k-offset, first 16B
  const int asw2 = (qh * 32 + 16) ^ ((lr & 7) << 4);// second 16B
  const int boff = (wc + lr) * 64 + ((qh ^ (lr & 3)) << 4);

  f32x4 acc[4][4] = {};

#define STAGE_A(k0, buf)                                                     \
  {                                                                          \
    char* d_ = (char*)&smA[buf][0] + w * 1024;                               \
    const float* s_ = gA + (k0);                                             \
    gload_lds16(s_ + 0 * 32 * NL, d_ + 0 * 4096);                            \
    gload_lds16(s_ + 1 * 32 * NL, d_ + 1 * 4096);                            \
    gload_lds16(s_ + 2 * 32 * NL, d_ + 2 * 4096);                            \
    gload_lds16(s_ + 3 * 32 * NL, d_ + 3 * 4096);                            \
  }
#define STAGE_B(k0, buf)                                                     \
  {                                                                          \
    char* d_ = (char*)&smB[buf][0] + w * 1024;                               \
    const unsigned short* s_ = gB + (k0);                                    \
    gload_lds16(s_, d_);                                                     \
    gload_lds16(s_ + 64 * NL, d_ + 4096);                                    \
  }

  STAGE_A(0, 0)
  STAGE_B(0, 0)
  __syncthreads();
  int cur = 0;
#pragma unroll 1
  for (int kt = 0; kt < 24; ++kt) {
    if (kt < 23) {
      STAGE_A((kt + 1) * 32, cur ^ 1)
      STAGE_B((kt + 1) * 32, cur ^ 1)
    }
    const char* A  = (const char*)&smA[cur][0];
    const char* Bb = (const char*)&smB[cur][0];
    bf16x8 fa[4], fb[4];
#pragma unroll
    for (int m = 0; m < 4; ++m) {
      fl4 a0 = *(const fl4*)(A + aoff + m * 2048 + asw1);
      fl4 a1 = *(const fl4*)(A + aoff + m * 2048 + asw2);
      fa[m] = cvt_bf8(a0, a1);
    }
#pragma unroll
    for (int n = 0; n < 4; ++n)
      fb[n] = *(const bf16x8*)(Bb + boff + n * 1024);
#pragma unroll
    for (int m = 0; m < 4; ++m)
#pragma unroll
      for (int n = 0; n < 4; ++n)
        acc[m][n] = __builtin_amdgcn_mfma_f32_16x16x32_bf16(fa[m], fb[n], acc[m][n], 0, 0, 0);
    __syncthreads();
    cur ^= 1;
  }
#undef STAGE_A
#undef STAGE_B
  // epilogue: C/D layout col = lane&15, row = (lane>>4)*4 + reg
#pragma unroll
  for (int m = 0; m < 4; ++m) {
    const long rbase = m0 + wr + m * 16 + qh * 4;
#pragma unroll
    for (int n = 0; n < 4; ++n) {
      const long col = n0 + wc + n * 16 + lr;
#pragma unroll
      for (int r = 0; r < 4; ++r)
        p[(rbase + r) * NL + col] = f2bf(acc[m][n][r]);
    }
  }
}

// ---------------- kernel 3: sq[i] = sum_g p[i,g]^2 ----------------
__global__ __launch_bounds__(256) void k_sq(const unsigned short* __restrict__ p,
                                            float* __restrict__ sq) {
  const int row = blockIdx.x * 4 + (threadIdx.x >> 6);
  const int l = threadIdx.x & 63;
  const unsigned short* pr = p + (long)row * NL;
  float s = 0.f;
#pragma unroll
  for (int c = 0; c < 3; ++c) {
    u16x4 v = *(const u16x4*)(pr + (c * 64 + l) * 4);
#pragma unroll
    for (int j = 0; j < 4; ++j) {
      float f = __builtin_bit_cast(float, ((unsigned)v[j]) << 16);
      s += f * f;
    }
  }
#pragma unroll
  for (int d = 32; d >= 1; d >>= 1) s += __shfl_xor(s, d, 64);
  if (l == 0) sq[row] = s;
}

// ------- kernel 4: per-batch gram + epilogue sq[s]+sq[t]-2*gram -------
__global__ __launch_bounds__(256) void k_gram(const unsigned short* __restrict__ p,
                                              const float* __restrict__ sq,
                                              float* __restrict__ out) {
  __shared__ __align__(16) unsigned short smA[2][128 * 32];
  __shared__ __align__(16) unsigned short smB[2][128 * 32];
  const int tid = threadIdx.x;
  const int w = tid >> 6, l = tid & 63;
  const int wg = ((blockIdx.x & 7) * 128) + (blockIdx.x >> 3);
  const int batch = wg >> 4, tile = wg & 15;
  const int mt = tile >> 2, nt = tile & 3;
  const unsigned short* pb = p + (long)batch * NS * NL;
  const long m0 = (long)mt * 128, n0 = (long)nt * 128;
  const int wr = (w >> 1) * 64, wc = (w & 1) * 64;

  const int srow = tid >> 2;
  const int scol = ((tid & 3) ^ (srow & 3)) * 8; // pre-swizzled source col (shorts)
  const unsigned short* gA = pb + (m0 + srow) * (long)NL + scol;
  const unsigned short* gB = pb + (n0 + srow) * (long)NL + scol;

  const int qh = l >> 4, lr = l & 15;
  const int aoff = (wr + lr) * 64 + ((qh ^ (lr & 3)) << 4);
  const int boff = (wc + lr) * 64 + ((qh ^ (lr & 3)) << 4);

  f32x4 acc[4][4] = {};

#define STAGE2(k0, buf)                                                      \
  {                                                                          \
    char* da_ = (char*)&smA[buf][0] + w * 1024;                              \
    char* db_ = (char*)&smB[buf][0] + w * 1024;                              \
    gload_lds16(gA + (k0), da_);                                             \
    gload_lds16(gA + (k0) + 64 * NL, da_ + 4096);                            \
    gload_lds16(gB + (k0), db_);                                             \
    gload_lds16(gB + (k0) + 64 * NL, db_ + 4096);                            \
  }

  STAGE2(0, 0)
  __syncthreads();
  int cur = 0;
#pragma unroll 1
  for (int kt = 0; kt < 24; ++kt) {
    if (kt < 23) STAGE2((kt + 1) * 32, cur ^ 1)
    const char* A  = (const char*)&smA[cur][0];
    const char* Bb = (const char*)&smB[cur][0];
    bf16x8 fa[4], fb[4];
#pragma unroll
    for (int m = 0; m < 4; ++m)
      fa[m] = *(const bf16x8*)(A + aoff + m * 1024);
#pragma unroll
    for (int n = 0; n < 4; ++n)
      fb[n] = *(const bf16x8*)(Bb + boff + n * 1024);
#pragma unroll
    for (int m = 0; m < 4; ++m)
#pragma unroll
      for (int n = 0; n < 4; ++n)
        acc[m][n] = __builtin_amdgcn_mfma_f32_16x16x32_bf16(fa[m], fb[n], acc[m][n], 0, 0, 0);
    __syncthreads();
    cur ^= 1;
  }
#undef STAGE2
  const float* sqb = sq + batch * NS;
  float* outb = out + (long)batch * NS * NS;
  float sqc[4];
#pragma unroll
  for (int n = 0; n < 4; ++n) sqc[n] = sqb[n0 + wc + n * 16 + lr];
#pragma unroll
  for (int m = 0; m < 4; ++m) {
#pragma unroll
    for (int r = 0; r < 4; ++r) {
      const long row = m0 + wr + m * 16 + qh * 4 + r;
      const float sr = sqb[row];
#pragma unroll
      for (int n = 0; n < 4; ++n) {
        const long col = n0 + wc + n * 16 + lr;
        outb[row * NS + col] = sr + sqc[n] - 2.0f * acc[m][n][r];
      }
    }
  }
}

extern "C" void kernel_launch(void* const* d_in, const int* in_sizes, int n_in,
                              void* d_out, int out_size, void* d_ws, size_t ws_size,
                              hipStream_t stream) {
  (void)in_sizes; (void)n_in; (void)out_size; (void)ws_size;
  const float* x = (const float*)d_in[0]; // [B,S,L] fp32
  const float* b = (const float*)d_in[1]; // [L,L] fp32
  float* out = (float*)d_out;             // [B,S,S] fp32
  char* ws = (char*)d_ws;
  unsigned short* bb = (unsigned short*)ws;              // 1,179,648 B
  float* sq          = (float*)(ws + 1179648);           //   131,072 B
  unsigned short* p  = (unsigned short*)(ws + 1310720);  // 50,331,648 B

  k_cvt_b<<<576, 256, 0, stream>>>(b, bb);
  k_proj <<<1536, 256, 0, stream>>>(x, bb, p);
  k_sq   <<<8192, 256, 0, stream>>>(p, sq);
  k_gram <<<1024, 256, 0, stream>>>(p, sq, out);
}